// Round 7
// baseline (9803.330 us; speedup 1.0000x reference)
//
#include <hip/hip_runtime.h>
#include <cstddef>
#include <cstdint>

// Pointer-network decoder, B=64, T=128, D=512, H=512.
// Round 7: fence-free persistent decoder (r6 structure) hardened:
//  - flag store is RELEASE at SYSTEM scope (orders data ahead of flag at the
//    coherence point; release emits wbl2+waitcnt, NOT an invalidate, so the
//    read-only tables stay L2-warm)
//  - all cross-block data atomics at SYSTEM scope (guaranteed L1/L2 bypass)
//  - balanced accumulation trees (2-acc dot slices, 4-acc attn) to cut
//    fp divergence vs the numpy reference.

#define NEGV (-1e9f)

static constexpr int T = 128;
static constexpr int NB = 256, NTHR = 256;
static constexpr int BG = 16;            // batches per group

// ---- workspace layout (element offsets, fp32) ----
static constexpr size_t OFF_FLAGS = 0;                        // 256 ints: flags[4][64]
static constexpr size_t OFF_SEL  = 256;                       // 64 ints
static constexpr size_t OFF_H    = 512;                       // [64][512] h      (atomic)
static constexpr size_t OFF_C    = OFF_H    + 64*512;         // [64][512] c      (block-private)
static constexpr size_t OFF_HL   = OFF_C    + 64*512;         // [64][512] h_lstm (atomic)
static constexpr size_t OFF_INP  = OFF_HL   + 64*512;         // [64][512] inp    (atomic)
static constexpr size_t OFF_HW   = OFF_INP  + 64*512;         // [64][512] hW2+b  (atomic)
static constexpr size_t OFF_X0W  = OFF_HW   + 64*512;         // [2048]
static constexpr size_t OFF_XW   = OFF_X0W  + 2048;           // [8192][2048]
static constexpr size_t OFF_CTX  = OFF_XW   + (size_t)8192*2048; // [8192][512]
static constexpr size_t OFF_CWO  = OFF_CTX  + (size_t)8192*512;  // [8192][512]

__device__ __forceinline__ float sigf(float x) { return 1.0f / (1.0f + expf(-x)); }

// ---- cache-bypassing (coherence-point) relaxed atomics, SYSTEM scope ----
__device__ __forceinline__ float aload(const float* p) {
  return __hip_atomic_load(p, __ATOMIC_RELAXED, __HIP_MEMORY_SCOPE_SYSTEM);
}
__device__ __forceinline__ void astore(float* p, float v) {
  __hip_atomic_store(p, v, __ATOMIC_RELAXED, __HIP_MEMORY_SCOPE_SYSTEM);
}
__device__ __forceinline__ float2 aload2(const float* p) {
  union { unsigned long long u; float2 f; } c;
  c.u = __hip_atomic_load((const unsigned long long*)p, __ATOMIC_RELAXED,
                          __HIP_MEMORY_SCOPE_SYSTEM);
  return c.f;
}
__device__ __forceinline__ void astore2(float* p, float2 v) {
  union { unsigned long long u; float2 f; } c; c.f = v;
  __hip_atomic_store((unsigned long long*)p, c.u, __ATOMIC_RELAXED,
                     __HIP_MEMORY_SCOPE_SYSTEM);
}

// ---- group barrier: per-wave vmcnt drain (__syncthreads) -> RELEASE flag
// store -> relaxed poll. No acquire-invalidate anywhere: consumers read shared
// data only via bypassing atomics, so caches can't serve stale values. ----
__device__ __forceinline__ void gridbar(int* gflags, int target, int gl, int t) {
  __syncthreads();                      // drains vmcnt: all this block's stores at LLC
  if (t == 0)
    __hip_atomic_store(&gflags[gl], target, __ATOMIC_RELEASE, __HIP_MEMORY_SCOPE_SYSTEM);
  if (t < 64) {
    int miss = 0;
    for (;;) {
      int f = __hip_atomic_load(&gflags[t], __ATOMIC_RELAXED, __HIP_MEMORY_SCOPE_SYSTEM);
      if (__all(f >= target)) break;
      __builtin_amdgcn_s_sleep(1);
      if (++miss > 100000000) break;    // liveness escape hatch
    }
  }
  __syncthreads();
  asm volatile("" ::: "memory");        // no hoisting of data loads above the poll
}

// ---------------- precompute: x0 row ----------------
__global__ __launch_bounds__(256) void x0w_kernel(
    const float* __restrict__ input0, const float* __restrict__ W_ih,
    const float* __restrict__ b_ih, const float* __restrict__ b_hh,
    float* __restrict__ x0w) {
  int wid = (blockIdx.x * 256 + threadIdx.x) >> 6;
  int l = threadIdx.x & 63;
  const float* wr = W_ih + (size_t)wid * 512;
  float acc = 0.f;
  #pragma unroll
  for (int q = 0; q < 8; ++q) acc += input0[l*8+q] * wr[l*8+q];
  #pragma unroll
  for (int off = 32; off; off >>= 1) acc += __shfl_xor(acc, off, 64);
  if (l == 0) x0w[wid] = acc + b_ih[wid] + b_hh[wid];
}

// ---------------- precompute: tiled fp32 GEMM, C = A@B^T + bias1 + bias2 ----------------
__global__ __launch_bounds__(256) void gemm_abt(
    const float* __restrict__ A, const float* __restrict__ Bm,
    const float* __restrict__ bias1, const float* __restrict__ bias2,
    float* __restrict__ C, int M, int N, int K, int ldb) {
  __shared__ float As[16][132];
  __shared__ float Bs[16][132];
  const int t = threadIdx.x;
  const int tx = t & 15, ty = t >> 4;
  const int mbase = blockIdx.y * 128, nbase = blockIdx.x * 128;
  float acc[8][8] = {};
  for (int kc = 0; kc < K; kc += 16) {
    __syncthreads();
    #pragma unroll
    for (int r = 0; r < 2; ++r) {
      int q = r * 256 + t;
      int row = q >> 2, kq = (q & 3) * 4;
      float4 va = *(const float4*)&A[(size_t)(mbase + row) * K + kc + kq];
      As[kq+0][row] = va.x; As[kq+1][row] = va.y; As[kq+2][row] = va.z; As[kq+3][row] = va.w;
      float4 vb = *(const float4*)&Bm[(size_t)(nbase + row) * ldb + kc + kq];
      Bs[kq+0][row] = vb.x; Bs[kq+1][row] = vb.y; Bs[kq+2][row] = vb.z; Bs[kq+3][row] = vb.w;
    }
    __syncthreads();
    #pragma unroll
    for (int kk = 0; kk < 16; ++kk) {
      float a[8], b[8];
      *(float4*)(a)   = *(const float4*)&As[kk][ty*8];
      *(float4*)(a+4) = *(const float4*)&As[kk][ty*8+4];
      *(float4*)(b)   = *(const float4*)&Bs[kk][tx*8];
      *(float4*)(b+4) = *(const float4*)&Bs[kk][tx*8+4];
      #pragma unroll
      for (int i = 0; i < 8; ++i)
        #pragma unroll
        for (int j = 0; j < 8; ++j)
          acc[i][j] = fmaf(a[i], b[j], acc[i][j]);
    }
  }
  float bv[8];
  #pragma unroll
  for (int q = 0; q < 8; ++q) {
    int n = nbase + tx*8 + q;
    bv[q] = (bias1 ? bias1[n] : 0.f) + (bias2 ? bias2[n] : 0.f);
  }
  #pragma unroll
  for (int i = 0; i < 8; ++i) {
    size_t m = (size_t)(mbase + ty*8 + i);
    float4 o0 = make_float4(acc[i][0]+bv[0], acc[i][1]+bv[1], acc[i][2]+bv[2], acc[i][3]+bv[3]);
    float4 o1 = make_float4(acc[i][4]+bv[4], acc[i][5]+bv[5], acc[i][6]+bv[6], acc[i][7]+bv[7]);
    *(float4*)&C[m * N + nbase + tx*8]     = o0;
    *(float4*)&C[m * N + nbase + tx*8 + 4] = o1;
  }
}

// ---------------- the persistent decoder ----------------
// LDS weight layout: row length 576 floats; chunk c (of 16, 32 floats each) at
// row*576 + c*36 (b128-aligned, conflict-free).
__global__ __launch_bounds__(256) void decoder_kernel(
    const float* __restrict__ h0, const float* __restrict__ c0,
    const float* __restrict__ cmask,
    const float* __restrict__ W_hh,
    const float* __restrict__ W_inp, const float* __restrict__ b_inp_,
    const float* __restrict__ W_out, const float* __restrict__ b_out_,
    const float* __restrict__ vvec,
    float* __restrict__ ws, float* __restrict__ out) {
  __shared__ float swA[32*576];   // W_hh rows [gate*8+rl], chunk-padded (73.7 KB)
  __shared__ float swB[16*576];   // [0..7] W_inp rows, [8..15] W_out2 rows (36.9 KB)
  __shared__ float sph[512];      // A/B handoff; CD: scores[0..127], alpha[128..255]
  __shared__ float smask[128];    // CD-block-private running mask
  __shared__ float sbias[16];
  __shared__ float s_mlen;

  int* flagsp = (int*)ws;
  int* selp   = (int*)(ws + OFF_SEL);
  float* hrow  = ws + OFF_H;
  float* crow  = ws + OFF_C;
  float* hlrow = ws + OFF_HL;
  float* inpp  = ws + OFF_INP;
  float* hwp   = ws + OFF_HW;
  const float* x0wp = ws + OFF_X0W;
  const float* xwp  = ws + OFF_XW;
  const float* ctxp = ws + OFF_CTX;
  const float* cwop = ws + OFF_CWO;

  float* out_scores = out;
  float* out_ptrs   = out + (size_t)64*128*128;
  float* out_hf     = out_ptrs + 64*128;
  float* out_cf     = out_hf + 64*512;

  const int g = blockIdx.x, t = threadIdx.x;
  const int gg = g >> 6, gl = g & 63;       // group, block-in-group
  const int w = t >> 6, l = t & 63;
  const int bl = t >> 4, js = t & 15;       // phase A/B: (batch-local, j-slice)
  int* gflags = flagsp + gg * 64;
  int bar = 0;
  const int bCD = gg*BG + gl;               // CD phase: batch of this block (gl<16)

  // ---- stage this block's weight rows into LDS (chunk-padded) ----
  {
    const int a = t >> 3, seg = t & 7;      // swA: 32 rows, 8 segs of 64 floats
    const int gate = a >> 3, rl = a & 7;
    const float* srcrow = W_hh + ((size_t)(gate*512 + gl*8 + rl)) * 512;
    #pragma unroll
    for (int c2 = 0; c2 < 2; ++c2) {
      const int ch = seg*2 + c2;
      const float4* s4 = (const float4*)&srcrow[ch*32];
      float4* d4 = (float4*)&swA[a*576 + ch*36];
      #pragma unroll
      for (int u = 0; u < 8; ++u) d4[u] = s4[u];
    }
    const int a2 = t >> 4, seg2 = t & 15;   // swB: 16 rows, 16 segs of 32 floats
    const float* srcrow2 = (a2 < 8) ? (W_inp + (size_t)(gl*8 + a2) * 512)
                                    : (W_out + (size_t)(gl*8 + a2 - 8) * 1024 + 512);
    const float4* s42 = (const float4*)&srcrow2[seg2*32];
    float4* d42 = (float4*)&swB[a2*576 + seg2*36];
    #pragma unroll
    for (int u = 0; u < 8; ++u) d42[u] = s42[u];
    if (t < 16) sbias[t] = (t < 8) ? b_inp_[gl*8 + t] : b_out_[gl*8 + t - 8];
  }

  // ---- init: h (atomic, blocks gl<16), c (OWNER block only), CD mask/max_len ----
  {
    const int idx = gl * NTHR + t;          // 0..16383 within group
    const int base = gg * 8192;
    if (idx < 4096) {                       // h: float2 idx (blocks gl<16)
      const float2 v = *(const float2*)&h0[base + idx*2];
      astore2(&hrow[base + idx*2], v);
    }
    // c: block gl owns rows gl*8..gl*8+7 of all 16 group batches (normal memory,
    // only ever read/written by this block)
    if (t < 128) {
      const int bb = gg*BG + (t >> 3), rr = gl*8 + (t & 7);
      crow[(size_t)bb*512 + rr] = c0[(size_t)bb*512 + rr];
    }
    if (gl < BG) {
      if (t < 128) smask[t] = cmask[bCD*128 + t];
      __syncthreads();
      if (t < 64) {
        float m_ = smask[t] + smask[64 + t];
        #pragma unroll
        for (int off = 32; off; off >>= 1) m_ += __shfl_xor(m_, off, 64);
        if (t == 0) s_mlen = m_;
      }
    }
  }
  gridbar(gflags, ++bar, gl, t);

  // per-lane constants for CD e-phase
  float vreg[8];
  *(float4*)(vreg)   = *(const float4*)&vvec[l*8];
  *(float4*)(vreg+4) = *(const float4*)&vvec[l*8+4];

  for (int s = 0; s < T; ++s) {
    // ====== PHASE A: gates -> c_t, h_lstm (row-split) ======
    {
      const int b = gg*BG + bl;
      const float* hb = hrow + (size_t)b*512 + js*32;
      float hbuf[32];
      #pragma unroll
      for (int q = 0; q < 16; ++q) *(float2*)&hbuf[q*2] = aload2(&hb[q*2]);
      float acc[32];
      const float* wbase = &swA[js*36];
      #pragma unroll
      for (int a = 0; a < 32; ++a) {
        const float* wr = wbase + a*576;
        float s0 = 0.f, s1 = 0.f;
        #pragma unroll
        for (int j = 0; j < 32; j += 8) {
          float4 w0 = *(const float4*)&wr[j];
          float4 w1 = *(const float4*)&wr[j+4];
          s0 = fmaf(hbuf[j+0], w0.x, fmaf(hbuf[j+1], w0.y,
               fmaf(hbuf[j+2], w0.z, fmaf(hbuf[j+3], w0.w, s0))));
          s1 = fmaf(hbuf[j+4], w1.x, fmaf(hbuf[j+5], w1.y,
               fmaf(hbuf[j+6], w1.z, fmaf(hbuf[j+7], w1.w, s1))));
        }
        acc[a] = s0 + s1;
      }
      #pragma unroll
      for (int a = 0; a < 32; ++a) {
        acc[a] += __shfl_xor(acc[a], 1, 64);
        acc[a] += __shfl_xor(acc[a], 2, 64);
        acc[a] += __shfl_xor(acc[a], 4, 64);
        acc[a] += __shfl_xor(acc[a], 8, 64);
      }
      if (js == 0) {
        #pragma unroll
        for (int a = 0; a < 32; ++a) sph[bl*32 + a] = acc[a];
      }
      __syncthreads();
      if (js < 8) {
        const int r = gl*8 + js;
        float pi = sph[bl*32 + 0*8 + js];
        float pf = sph[bl*32 + 1*8 + js];
        float pg = sph[bl*32 + 2*8 + js];
        float po = sph[bl*32 + 3*8 + js];
        const float* xrow;
        if (s == 0) xrow = x0wp;
        else {
          int se = __hip_atomic_load(&selp[b], __ATOMIC_RELAXED, __HIP_MEMORY_SCOPE_SYSTEM);
          xrow = xwp + ((size_t)b*128 + (size_t)se) * 2048;
        }
        float gi  = pi + xrow[0*512 + r];
        float gf  = pf + xrow[1*512 + r];
        float gg2 = pg + xrow[2*512 + r];
        float go  = po + xrow[3*512 + r];
        float cp = crow[(size_t)b*512 + r];           // block-private, cached
        float ct = sigf(gf)*cp + sigf(gi)*tanhf(gg2);
        crow[(size_t)b*512 + r] = ct;
        astore(&hlrow[(size_t)b*512 + r], sigf(go)*tanhf(ct));
      }
    }
    gridbar(gflags, ++bar, gl, t);

    // ====== PHASE B: inp = hl@W_inp^T + b ; hw = hl@Wout2^T + b (row-split) ======
    {
      const int b = gg*BG + bl;
      const float* hb = hlrow + (size_t)b*512 + js*32;
      float hbuf[32];
      #pragma unroll
      for (int q = 0; q < 16; ++q) *(float2*)&hbuf[q*2] = aload2(&hb[q*2]);
      float acc[16];
      const float* wbase = &swB[js*36];
      #pragma unroll
      for (int a = 0; a < 16; ++a) {
        const float* wr = wbase + a*576;
        float s0 = 0.f, s1 = 0.f;
        #pragma unroll
        for (int j = 0; j < 32; j += 8) {
          float4 w0 = *(const float4*)&wr[j];
          float4 w1 = *(const float4*)&wr[j+4];
          s0 = fmaf(hbuf[j+0], w0.x, fmaf(hbuf[j+1], w0.y,
               fmaf(hbuf[j+2], w0.z, fmaf(hbuf[j+3], w0.w, s0))));
          s1 = fmaf(hbuf[j+4], w1.x, fmaf(hbuf[j+5], w1.y,
               fmaf(hbuf[j+6], w1.z, fmaf(hbuf[j+7], w1.w, s1))));
        }
        acc[a] = s0 + s1;
      }
      #pragma unroll
      for (int a = 0; a < 16; ++a) {
        acc[a] += __shfl_xor(acc[a], 1, 64);
        acc[a] += __shfl_xor(acc[a], 2, 64);
        acc[a] += __shfl_xor(acc[a], 4, 64);
        acc[a] += __shfl_xor(acc[a], 8, 64);
      }
      if (js == 0) {
        #pragma unroll
        for (int a = 0; a < 16; ++a) sph[bl*16 + a] = acc[a];
      }
      __syncthreads();
      if (js < 8) {
        const int r = gl*8 + js;
        astore(&inpp[(size_t)b*512 + r], sph[bl*16 + js]     + sbias[js]);
        astore(&hwp [(size_t)b*512 + r], sph[bl*16 + 8 + js] + sbias[8 + js]);
      }
    }
    gridbar(gflags, ++bar, gl, t);

    // ====== PHASE CD: e, softmax, selection, attn, h_t (1 block per batch) ======
    if (gl < BG) {
      const int b = bCD;
      float ii[8];
      *(float2*)(ii)   = aload2(&inpp[(size_t)b*512 + l*8]);
      *(float2*)(ii+2) = aload2(&inpp[(size_t)b*512 + l*8 + 2]);
      *(float2*)(ii+4) = aload2(&inpp[(size_t)b*512 + l*8 + 4]);
      *(float2*)(ii+6) = aload2(&inpp[(size_t)b*512 + l*8 + 6]);
      for (int q = 0; q < 32; ++q) {
        const int tc = w*32 + q;
        const float* cr = ctxp + ((size_t)(b*128 + tc))*512 + l*8;
        float4 c0_ = *(const float4*)cr;
        float4 c1_ = *(const float4*)(cr + 4);
        float acc = vreg[0]*tanhf(c0_.x + ii[0]) + vreg[1]*tanhf(c0_.y + ii[1])
                  + vreg[2]*tanhf(c0_.z + ii[2]) + vreg[3]*tanhf(c0_.w + ii[3])
                  + vreg[4]*tanhf(c1_.x + ii[4]) + vreg[5]*tanhf(c1_.y + ii[5])
                  + vreg[6]*tanhf(c1_.z + ii[6]) + vreg[7]*tanhf(c1_.w + ii[7]);
        #pragma unroll
        for (int off = 32; off; off >>= 1) acc += __shfl_xor(acc, off, 64);
        if (l == 0) sph[tc] = (smask[tc] > 0.f) ? acc : NEGV;   // masked score
      }
      __syncthreads();
      if (t < 128) out_scores[((size_t)b*128 + s)*128 + t] = sph[t];
      if (w == 0) {
        float s0 = sph[l], s1 = sph[64 + l];
        float mx = fmaxf(s0, s1);
        #pragma unroll
        for (int off = 32; off; off >>= 1) mx = fmaxf(mx, __shfl_xor(mx, off, 64));
        float x0 = expf(s0 - mx), x1 = expf(s1 - mx);
        float sum = x0 + x1;
        #pragma unroll
        for (int off = 32; off; off >>= 1) sum += __shfl_xor(sum, off, 64);
        float a0 = x0 / sum, a1 = x1 / sum;
        sph[128 + l] = a0; sph[192 + l] = a1;
        // selection
        float p0 = a0 * smask[l], p1 = a1 * smask[64 + l];
        float pv; int pi;
        if (p1 > p0) { pv = p1; pi = l + 64; } else { pv = p0; pi = l; }
        #pragma unroll
        for (int off = 32; off; off >>= 1) {
          float ov = __shfl_xor(pv, off, 64);
          int   oi = __shfl_xor(pi, off, 64);
          if (ov > pv || (ov == pv && oi < pi)) { pv = ov; pi = oi; }
        }
        if (l == 0) {
          int se = (s_mlen > (float)s) ? pi : s;
          __hip_atomic_store(&selp[b], se, __ATOMIC_RELAXED, __HIP_MEMORY_SCOPE_SYSTEM);
          smask[se] = 0.f;
          out_ptrs[b*128 + s] = (float)se;
        }
      }
      __syncthreads();
      {
        const int i0 = t*2;
        const float* cw = cwop + (size_t)b*128*512 + i0;
        float ax0=0.f, ax1=0.f, ax2=0.f, ax3=0.f;
        float ay0=0.f, ay1=0.f, ay2=0.f, ay3=0.f;
        #pragma unroll 8
        for (int tc = 0; tc < 128; tc += 4) {
          float2 c0v = *(const float2*)&cw[(size_t)(tc+0)*512];
          float2 c1v = *(const float2*)&cw[(size_t)(tc+1)*512];
          float2 c2v = *(const float2*)&cw[(size_t)(tc+2)*512];
          float2 c3v = *(const float2*)&cw[(size_t)(tc+3)*512];
          float al0 = sph[128+tc+0], al1 = sph[128+tc+1];
          float al2 = sph[128+tc+2], al3 = sph[128+tc+3];
          ax0 = fmaf(al0, c0v.x, ax0); ay0 = fmaf(al0, c0v.y, ay0);
          ax1 = fmaf(al1, c1v.x, ax1); ay1 = fmaf(al1, c1v.y, ay1);
          ax2 = fmaf(al2, c2v.x, ax2); ay2 = fmaf(al2, c2v.y, ay2);
          ax3 = fmaf(al3, c3v.x, ax3); ay3 = fmaf(al3, c3v.y, ay3);
        }
        float2 hwv = aload2(&hwp[(size_t)b*512 + i0]);
        float2 hv;
        hv.x = tanhf(hwv.x + ((ax0 + ax1) + (ax2 + ax3)));
        hv.y = tanhf(hwv.y + ((ay0 + ay1) + (ay2 + ay3)));
        astore2(&hrow[(size_t)b*512 + i0], hv);
      }
    }
    gridbar(gflags, ++bar, gl, t);
  }

  // ---- epilogue: h_f (blocks gl<16, atomic), c_f (owning block only) ----
  {
    const int idx = gl * NTHR + t;
    const int base = gg * 8192;
    if (idx < 4096) {
      float2 v = aload2(&hrow[base + idx*2]);
      *(float2*)&out_hf[base + idx*2] = v;
    }
    if (t < 128) {                        // c rows gl*8..+7, group batches
      const int bb = gg*BG + (t >> 3), rr = gl*8 + (t & 7);
      out_cf[(size_t)bb*512 + rr] = crow[(size_t)bb*512 + rr];
    }
  }
}

extern "C" void kernel_launch(void* const* d_in, const int* in_sizes, int n_in,
                              void* d_out, int out_size, void* d_ws, size_t ws_size,
                              hipStream_t stream) {
  (void)in_sizes; (void)n_in; (void)out_size; (void)ws_size;
  const float* inputs    = (const float*)d_in[0];
  const float* h0        = (const float*)d_in[1];
  const float* c0        = (const float*)d_in[2];
  const float* candidate = (const float*)d_in[3];
  const float* cmask     = (const float*)d_in[4];
  const float* input0    = (const float*)d_in[5];
  const float* W_ih      = (const float*)d_in[6];
  const float* b_ih      = (const float*)d_in[7];
  const float* W_hh      = (const float*)d_in[8];
  const float* b_hh      = (const float*)d_in[9];
  const float* W_out     = (const float*)d_in[10];
  const float* b_out     = (const float*)d_in[11];
  const float* W_inp     = (const float*)d_in[12];
  const float* b_inp     = (const float*)d_in[13];
  const float* W_ctx     = (const float*)d_in[14];
  const float* b_ctx     = (const float*)d_in[15];
  const float* v         = (const float*)d_in[16];
  float* ws  = (float*)d_ws;
  float* outp = (float*)d_out;

  // zero barrier flags + sel
  (void)hipMemsetAsync(d_ws, 0, 2048, stream);

  // x0 row: input0 @ W_ih^T + b_ih + b_hh
  x0w_kernel<<<512, 256, 0, stream>>>(input0, W_ih, b_ih, b_hh, ws + OFF_X0W);

  // xW table: inputs(8192,512) @ W_ih(2048,512)^T + b_ih + b_hh
  gemm_abt<<<dim3(16, 64), 256, 0, stream>>>(inputs, W_ih, b_ih, b_hh,
                                             ws + OFF_XW, 8192, 2048, 512, 512);
  // ctx_lin: candidate(8192,512) @ W_ctx(512,512)^T + b_ctx
  gemm_abt<<<dim3(4, 64), 256, 0, stream>>>(candidate, W_ctx, b_ctx, nullptr,
                                            ws + OFF_CTX, 8192, 512, 512, 512);
  // ctxWo: ctx_lin @ W_out[:, :512]^T   (W_out row stride 1024)
  gemm_abt<<<dim3(4, 64), 256, 0, stream>>>(ws + OFF_CTX, W_out, nullptr, nullptr,
                                            ws + OFF_CWO, 8192, 512, 512, 1024);

  decoder_kernel<<<NB, NTHR, 0, stream>>>(h0, c0, cmask, W_hh, W_inp, b_inp,
                                          W_out, b_out, v, ws, outp);
}